// Round 1
// baseline (966.001 us; speedup 1.0000x reference)
//
#include <hip/hip_runtime.h>
#include <math.h>

#define SEQL 8192
#define NH 16
#define HD 1024           // NH * 64
#define NM 128            // SEQL / 64
#define NN 256            // SEQL / 32
#define TSEL 25

// ---- workspace layout (float offsets) ----
#define OFF_KM     0                         // 1024  (zeroed, atomics)
#define OFF_KVSUM  1024                      // 16*4096 (zeroed, atomics)
#define OFF_KSUM   (1024 + 16*4096)          // 1024  (zeroed, atomics)
#define OFF_ZEND   (OFF_KSUM + 1024)
#define OFF_PQ     OFF_ZEND                  // 16*128*64
#define OFF_PK     (OFF_PQ + 16*128*64)      // 16*256*64
#define OFF_LUT    (OFF_PK + 16*256*64)      // 16*128*25 ints
#define OFF_KW     (OFF_LUT + 16*128*25)     // 16*4096

// K1: km_sum[h*64+d] = sum_l k[l][h][d]   (divide by L at use sites)
__global__ void k_mean(const float* __restrict__ k, float* __restrict__ kmsum) {
    int b = blockIdx.x, t = threadIdx.x;
    int l0 = b * 32;
    float s0 = 0.f, s1 = 0.f, s2 = 0.f, s3 = 0.f;
    for (int l = 0; l < 32; l++) {
        const float* row = k + (size_t)(l0 + l) * HD;
        s0 += row[t]; s1 += row[t + 256]; s2 += row[t + 512]; s3 += row[t + 768];
    }
    atomicAdd(&kmsum[t], s0);
    atomicAdd(&kmsum[t + 256], s1);
    atomicAdd(&kmsum[t + 512], s2);
    atomicAdd(&kmsum[t + 768], s3);
}

// K2a: pooled_q[(h*128+m)*64+d] = mean over 64 rows
__global__ void pool_q(const float* __restrict__ q, float* __restrict__ pq) {
    int b = blockIdx.x;
    int h = b >> 7, m = b & 127, d = threadIdx.x;
    const float* base = q + (size_t)m * 64 * HD + h * 64 + d;
    float s = 0.f;
    #pragma unroll 8
    for (int r = 0; r < 64; r++) s += base[(size_t)r * HD];
    pq[(size_t)b * 64 + d] = s * (1.f / 64.f);
}

// K2b: pooled_k[(h*256+n)*64+d] = mean over 32 rows of k minus key-mean
__global__ void pool_k(const float* __restrict__ k, const float* __restrict__ kmsum,
                       float* __restrict__ pk) {
    int b = blockIdx.x;
    int h = b >> 8, n = b & 255, d = threadIdx.x;
    const float* base = k + (size_t)n * 32 * HD + h * 64 + d;
    float s = 0.f;
    #pragma unroll 8
    for (int r = 0; r < 32; r++) s += base[(size_t)r * HD];
    pk[(size_t)b * 64 + d] = s * (1.f / 32.f) - kmsum[h * 64 + d] * (1.f / (float)SEQL);
}

// K3: scores (f64 accum) + top-25 by all-pairs rank (ties: lower index wins,
// matching jax.lax.top_k), output sorted ascending by block index.
__global__ __launch_bounds__(256) void score_topk(const float* __restrict__ pq,
                                                  const float* __restrict__ pk,
                                                  int* __restrict__ lut) {
    __shared__ float pq_s[64];
    __shared__ float s_s[256];
    __shared__ int flag[256];
    int b = blockIdx.x;            // h*128 + m
    int h = b >> 7;
    int t = threadIdx.x;
    if (t < 64) pq_s[t] = pq[(size_t)b * 64 + t];
    __syncthreads();
    const float* kr = pk + ((size_t)h * 256 + t) * 64;
    double acc = 0.0;
    #pragma unroll 8
    for (int d = 0; d < 64; d++) acc += (double)pq_s[d] * (double)kr[d];
    float sc = (float)acc;
    s_s[t] = sc;
    __syncthreads();
    int cnt = 0;
    float si = s_s[t];
    for (int j = 0; j < 256; j++) {
        float sj = s_s[j];
        cnt += (sj > si) || (sj == si && j < t);
    }
    flag[t] = (cnt < TSEL) ? 1 : 0;
    __syncthreads();
    if (cnt < TSEL) {
        int pos = 0;
        for (int j = 0; j < t; j++) pos += flag[j];
        lut[(size_t)b * TSEL + pos] = t;
    }
}

// K5: kvsum[h][d][e] += sum_l k_fm[l][d]*v[l][e]; ksum[h][d] += sum_l k_fm[l][d]
// k_fm computed on the fly (softmax over D of raw k). One block = one h x 64 seq rows.
__global__ __launch_bounds__(256) void lin_kv(const float* __restrict__ k,
                                              const float* __restrict__ v,
                                              float* __restrict__ kvsum,
                                              float* __restrict__ ksum) {
    __shared__ float kf[64][68];
    __shared__ float vv[64][68];
    int b = blockIdx.x;
    int h = b >> 7, chunk = b & 127;
    int l0 = chunk * 64;
    int t = threadIdx.x;
    {   // stage 64x64 tiles, float4
        int row = t >> 2, d0 = (t & 3) * 16;
        const float4* ks4 = (const float4*)(k + (size_t)(l0 + row) * HD + h * 64 + d0);
        const float4* vs4 = (const float4*)(v + (size_t)(l0 + row) * HD + h * 64 + d0);
        float4* kd = (float4*)&kf[row][d0];
        float4* vd = (float4*)&vv[row][d0];
        #pragma unroll
        for (int i = 0; i < 4; i++) { kd[i] = ks4[i]; vd[i] = vs4[i]; }
    }
    __syncthreads();
    // softmax k rows in place (wave per 16 rows, lane = d)
    int wv = t >> 6, lane = t & 63;
    for (int rr = 0; rr < 16; rr++) {
        int r = wv * 16 + rr;
        float x = kf[r][lane];
        float mx = x;
        #pragma unroll
        for (int off = 1; off < 64; off <<= 1) mx = fmaxf(mx, __shfl_xor(mx, off, 64));
        float e = __expf(x - mx);
        float sm = e;
        #pragma unroll
        for (int off = 1; off < 64; off <<= 1) sm += __shfl_xor(sm, off, 64);
        kf[r][lane] = e / sm;
    }
    __syncthreads();
    // accumulate outer products: thread = (e, d-group of 16)
    int e_ = t & 63, dg = t >> 6;
    float acc[16];
    #pragma unroll
    for (int j = 0; j < 16; j++) acc[j] = 0.f;
    for (int l = 0; l < 64; l++) {
        float vl = vv[l][e_];
        const float4* k4 = (const float4*)&kf[l][dg * 16];
        float4 a = k4[0], b4 = k4[1], c4 = k4[2], d4 = k4[3];
        acc[0]  += a.x * vl;  acc[1]  += a.y * vl;  acc[2]  += a.z * vl;  acc[3]  += a.w * vl;
        acc[4]  += b4.x * vl; acc[5]  += b4.y * vl; acc[6]  += b4.z * vl; acc[7]  += b4.w * vl;
        acc[8]  += c4.x * vl; acc[9]  += c4.y * vl; acc[10] += c4.z * vl; acc[11] += c4.w * vl;
        acc[12] += d4.x * vl; acc[13] += d4.y * vl; acc[14] += d4.z * vl; acc[15] += d4.w * vl;
    }
    #pragma unroll
    for (int j = 0; j < 16; j++)
        atomicAdd(&kvsum[(size_t)h * 4096 + (dg * 16 + j) * 64 + e_], acc[j]);
    if (t < 64) {
        float s = 0.f;
        for (int l = 0; l < 64; l++) s += kf[l][t];
        atomicAdd(&ksum[h * 64 + t], s);
    }
}

// K6: KW[h][d][dd] = sum_e kvsum[h][d][e] * W[dd][e]
__global__ __launch_bounds__(256) void kw_mul(const float* __restrict__ kvsum,
                                              const float* __restrict__ W,
                                              float* __restrict__ KW) {
    __shared__ float kv[64][65];
    __shared__ float w[64][65];
    int h = blockIdx.x, t = threadIdx.x;
    for (int i = t; i < 4096; i += 256) {
        kv[i >> 6][i & 63] = kvsum[(size_t)h * 4096 + i];
        w[i >> 6][i & 63] = W[i];
    }
    __syncthreads();
    int dd = t & 63, dg = t >> 6;
    #pragma unroll
    for (int j = 0; j < 16; j++) {
        int d = dg * 16 + j;
        float a = 0.f;
        #pragma unroll 8
        for (int e = 0; e < 64; e++) a += kv[d][e] * w[dd][e];
        KW[(size_t)h * 4096 + d * 64 + dd] = a;
    }
}

// K7: block-sparse attention (the big one). One block per (h, m).
// thread = (row r 0..63, quarter g 0..3): q row chunk + O accumulator in regs,
// K(centered)/V staged in LDS, partial dots + xor-butterfly, online softmax.
__global__ __launch_bounds__(256) void sparse_attn(const float* __restrict__ q,
                                                   const float* __restrict__ k,
                                                   const float* __restrict__ v,
                                                   const float* __restrict__ kmsum,
                                                   const int* __restrict__ lut,
                                                   float* __restrict__ out) {
    __shared__ float kt[32][68];
    __shared__ float vt[32][68];
    __shared__ float km_s[64];
    __shared__ int lut_s[TSEL];
    int b = blockIdx.x;
    int h = b >> 7, m = b & 127;
    int t = threadIdx.x;
    int r = t >> 2, g = t & 3;
    if (t < 64) km_s[t] = kmsum[h * 64 + t] * (1.f / (float)SEQL);
    if (t < TSEL) lut_s[t] = lut[(size_t)b * TSEL + t];
    float qr[16];
    {
        const float4* q4 = (const float4*)(q + (size_t)(m * 64 + r) * HD + h * 64 + g * 16);
        float4 a = q4[0], b4 = q4[1], c4 = q4[2], d4 = q4[3];
        qr[0] = a.x;  qr[1] = a.y;  qr[2] = a.z;  qr[3] = a.w;
        qr[4] = b4.x; qr[5] = b4.y; qr[6] = b4.z; qr[7] = b4.w;
        qr[8] = c4.x; qr[9] = c4.y; qr[10] = c4.z; qr[11] = c4.w;
        qr[12] = d4.x; qr[13] = d4.y; qr[14] = d4.z; qr[15] = d4.w;
    }
    float O[16];
    #pragma unroll
    for (int j = 0; j < 16; j++) O[j] = 0.f;
    float m_i = -INFINITY, l_i = 0.f;
    int c_ = t >> 3, dd0 = (t & 7) * 8;
    __syncthreads();
    for (int ti = 0; ti < TSEL; ti++) {
        int n = lut_s[ti];
        {   // stage K (centered) and V: 32x64 each
            const float* kb = k + (size_t)(n * 32 + c_) * HD + h * 64 + dd0;
            const float* vb = v + (size_t)(n * 32 + c_) * HD + h * 64 + dd0;
            float4 ka = *(const float4*)kb;
            float4 kb2 = *(const float4*)(kb + 4);
            float4 va = *(const float4*)vb;
            float4 vb2 = *(const float4*)(vb + 4);
            ka.x -= km_s[dd0 + 0]; ka.y -= km_s[dd0 + 1]; ka.z -= km_s[dd0 + 2]; ka.w -= km_s[dd0 + 3];
            kb2.x -= km_s[dd0 + 4]; kb2.y -= km_s[dd0 + 5]; kb2.z -= km_s[dd0 + 6]; kb2.w -= km_s[dd0 + 7];
            *(float4*)&kt[c_][dd0] = ka;
            *(float4*)&kt[c_][dd0 + 4] = kb2;
            *(float4*)&vt[c_][dd0] = va;
            *(float4*)&vt[c_][dd0 + 4] = vb2;
        }
        __syncthreads();
        float ps[32];
        #pragma unroll
        for (int c = 0; c < 32; c++) {
            const float4* kr4 = (const float4*)&kt[c][g * 16];
            float4 a = kr4[0], b4 = kr4[1], c4 = kr4[2], d4 = kr4[3];
            float s = a.x * qr[0] + a.y * qr[1] + a.z * qr[2] + a.w * qr[3]
                    + b4.x * qr[4] + b4.y * qr[5] + b4.z * qr[6] + b4.w * qr[7]
                    + c4.x * qr[8] + c4.y * qr[9] + c4.z * qr[10] + c4.w * qr[11]
                    + d4.x * qr[12] + d4.y * qr[13] + d4.z * qr[14] + d4.w * qr[15];
            ps[c] = s;
        }
        #pragma unroll
        for (int c = 0; c < 32; c++) {
            ps[c] += __shfl_xor(ps[c], 1, 64);
            ps[c] += __shfl_xor(ps[c], 2, 64);
        }
        float mx = m_i;
        #pragma unroll
        for (int c = 0; c < 32; c++) { ps[c] *= 0.125f; mx = fmaxf(mx, ps[c]); }
        float alpha = __expf(m_i - mx);
        float sum = 0.f;
        #pragma unroll
        for (int c = 0; c < 32; c++) { float p = __expf(ps[c] - mx); ps[c] = p; sum += p; }
        m_i = mx;
        l_i = l_i * alpha + sum;
        #pragma unroll
        for (int j = 0; j < 16; j++) O[j] *= alpha;
        #pragma unroll
        for (int c = 0; c < 32; c++) {
            const float4* vr4 = (const float4*)&vt[c][g * 16];
            float4 a = vr4[0], b4 = vr4[1], c4 = vr4[2], d4 = vr4[3];
            float p = ps[c];
            O[0]  += p * a.x;  O[1]  += p * a.y;  O[2]  += p * a.z;  O[3]  += p * a.w;
            O[4]  += p * b4.x; O[5]  += p * b4.y; O[6]  += p * b4.z; O[7]  += p * b4.w;
            O[8]  += p * c4.x; O[9]  += p * c4.y; O[10] += p * c4.z; O[11] += p * c4.w;
            O[12] += p * d4.x; O[13] += p * d4.y; O[14] += p * d4.z; O[15] += p * d4.w;
        }
        __syncthreads();
    }
    float inv = 1.f / l_i;
    float* dst = out + (size_t)(m * 64 + r) * HD + h * 64 + g * 16;
    *(float4*)&dst[0]  = make_float4(O[0] * inv, O[1] * inv, O[2] * inv, O[3] * inv);
    *(float4*)&dst[4]  = make_float4(O[4] * inv, O[5] * inv, O[6] * inv, O[7] * inv);
    *(float4*)&dst[8]  = make_float4(O[8] * inv, O[9] * inv, O[10] * inv, O[11] * inv);
    *(float4*)&dst[12] = make_float4(O[12] * inv, O[13] * inv, O[14] * inv, O[15] * inv);
}

// K8: linear-branch output: out[l][h][dd] += (q_fm . KW[h][:,dd]) / denom + b[dd]
// One block = one h x 64 seq rows. q_fm computed in LDS; matvec: lane = row.
__global__ __launch_bounds__(256) void lin_out(const float* __restrict__ q,
                                               const float* __restrict__ KW,
                                               const float* __restrict__ ksum,
                                               const float* __restrict__ bproj,
                                               float* __restrict__ out) {
    __shared__ float qf[64][65];
    __shared__ float kwl[64][68];
    __shared__ float ks_s[64];
    __shared__ float b_s[64];
    __shared__ float denom_s[64];
    int b = blockIdx.x;
    int h = b >> 7, chunk = b & 127;
    int l0 = chunk * 64;
    int t = threadIdx.x;
    if (t < 64) { ks_s[t] = ksum[h * 64 + t]; b_s[t] = bproj[t]; }
    {   // stage q rows (scalar: qf pad 65) and KW (float4: pad 68)
        int row = t >> 2, d0 = (t & 3) * 16;
        const float* src = q + (size_t)(l0 + row) * HD + h * 64 + d0;
        #pragma unroll
        for (int j = 0; j < 16; j++) qf[row][d0 + j] = src[j];
        const float4* ks4 = (const float4*)(KW + (size_t)h * 4096 + row * 64 + d0);
        float4* kd = (float4*)&kwl[row][d0];
        #pragma unroll
        for (int i = 0; i < 4; i++) kd[i] = ks4[i];
    }
    __syncthreads();
    int wv = t >> 6, lane = t & 63;
    for (int rr = 0; rr < 16; rr++) {   // softmax q rows + denom
        int r = wv * 16 + rr;
        float x = qf[r][lane];
        float mx = x;
        #pragma unroll
        for (int off = 1; off < 64; off <<= 1) mx = fmaxf(mx, __shfl_xor(mx, off, 64));
        float e = __expf(x - mx);
        float sm = e;
        #pragma unroll
        for (int off = 1; off < 64; off <<= 1) sm += __shfl_xor(sm, off, 64);
        float fmv = e / sm;
        qf[r][lane] = fmv;
        float dp = fmv * ks_s[lane];
        #pragma unroll
        for (int off = 1; off < 64; off <<= 1) dp += __shfl_xor(dp, off, 64);
        if (lane == 0) denom_s[r] = dp + 1e-6f;
    }
    __syncthreads();
    // matvec: wave wv owns dd-chunk [wv*16, wv*16+16), lane = seq row
    float acc[16];
    #pragma unroll
    for (int j = 0; j < 16; j++) acc[j] = 0.f;
    for (int d = 0; d < 64; d++) {
        float qv = qf[lane][d];
        const float4* k4 = (const float4*)&kwl[d][wv * 16];
        float4 a = k4[0], b4 = k4[1], c4 = k4[2], d4 = k4[3];
        acc[0]  += qv * a.x;  acc[1]  += qv * a.y;  acc[2]  += qv * a.z;  acc[3]  += qv * a.w;
        acc[4]  += qv * b4.x; acc[5]  += qv * b4.y; acc[6]  += qv * b4.z; acc[7]  += qv * b4.w;
        acc[8]  += qv * c4.x; acc[9]  += qv * c4.y; acc[10] += qv * c4.z; acc[11] += qv * c4.w;
        acc[12] += qv * d4.x; acc[13] += qv * d4.y; acc[14] += qv * d4.z; acc[15] += qv * d4.w;
    }
    float invd = 1.f / denom_s[lane];
    float* dst = out + (size_t)(l0 + lane) * HD + h * 64 + wv * 16;
    #pragma unroll
    for (int j4 = 0; j4 < 4; j4++) {
        float4 o = *(float4*)&dst[j4 * 4];
        o.x += acc[j4 * 4 + 0] * invd + b_s[wv * 16 + j4 * 4 + 0];
        o.y += acc[j4 * 4 + 1] * invd + b_s[wv * 16 + j4 * 4 + 1];
        o.z += acc[j4 * 4 + 2] * invd + b_s[wv * 16 + j4 * 4 + 2];
        o.w += acc[j4 * 4 + 3] * invd + b_s[wv * 16 + j4 * 4 + 3];
        *(float4*)&dst[j4 * 4] = o;
    }
}

extern "C" void kernel_launch(void* const* d_in, const int* in_sizes, int n_in,
                              void* d_out, int out_size, void* d_ws, size_t ws_size,
                              hipStream_t stream) {
    const float* q  = (const float*)d_in[0];
    const float* k  = (const float*)d_in[1];
    const float* v  = (const float*)d_in[2];
    const float* W  = (const float*)d_in[3];
    const float* bp = (const float*)d_in[4];
    float* out = (float*)d_out;
    float* ws = (float*)d_ws;

    float* kmsum = ws + OFF_KM;
    float* kvsum = ws + OFF_KVSUM;
    float* ksum  = ws + OFF_KSUM;
    float* pq    = ws + OFF_PQ;
    float* pk    = ws + OFF_PK;
    int*   lut   = (int*)(ws + OFF_LUT);
    float* KW    = ws + OFF_KW;

    hipMemsetAsync(ws, 0, OFF_ZEND * sizeof(float), stream);
    k_mean<<<256, 256, 0, stream>>>(k, kmsum);
    pool_q<<<2048, 64, 0, stream>>>(q, pq);
    pool_k<<<4096, 64, 0, stream>>>(k, kmsum, pk);
    score_topk<<<2048, 256, 0, stream>>>(pq, pk, lut);
    lin_kv<<<2048, 256, 0, stream>>>(k, v, kvsum, ksum);
    kw_mul<<<16, 256, 0, stream>>>(kvsum, W, KW);
    sparse_attn<<<2048, 256, 0, stream>>>(q, k, v, kmsum, lut, out);
    lin_out<<<2048, 256, 0, stream>>>(q, KW, ksum, bp, out);
}

// Round 2
// 458.444 us; speedup vs baseline: 2.1071x; 2.1071x over previous
//
#include <hip/hip_runtime.h>
#include <math.h>

#define SEQL 8192
#define NH 16
#define HD 1024           // NH * 64
#define NM 128            // SEQL / 64
#define NN 256            // SEQL / 32
#define TSEL 25

// ---- workspace layout (float offsets) ----
#define OFF_KM     0                         // 1024  (zeroed, atomics)
#define OFF_KVSUM  1024                      // 16*4096 (zeroed, atomics)
#define OFF_KSUM   (1024 + 16*4096)          // 1024  (zeroed, atomics)
#define OFF_ZEND   (OFF_KSUM + 1024)
#define OFF_PQ     OFF_ZEND                  // 16*128*64
#define OFF_PK     (OFF_PQ + 16*128*64)      // 16*256*64
#define OFF_LUT    (OFF_PK + 16*256*64)      // 16*128*25 ints
#define OFF_KW     (OFF_LUT + 16*128*25)     // 16*4096

typedef __attribute__((ext_vector_type(8))) short bf16x8;
typedef __attribute__((ext_vector_type(4))) float f32x4;

static __device__ inline short f2bf(float f) {
    union { float f; unsigned u; } c; c.f = f;
    unsigned r = (c.u + 0x7FFFu + ((c.u >> 16) & 1u)) >> 16;
    return (short)r;
}
static __device__ inline bf16x8 cvt8(float4 a, float4 b) {
    bf16x8 r;
    r[0] = f2bf(a.x); r[1] = f2bf(a.y); r[2] = f2bf(a.z); r[3] = f2bf(a.w);
    r[4] = f2bf(b.x); r[5] = f2bf(b.y); r[6] = f2bf(b.z); r[7] = f2bf(b.w);
    return r;
}

// K1: km_sum[h*64+d] = sum_l k[l][h][d]   (divide by L at use sites)
__global__ void k_mean(const float* __restrict__ k, float* __restrict__ kmsum) {
    int b = blockIdx.x, t = threadIdx.x;
    int l0 = b * 32;
    float s0 = 0.f, s1 = 0.f, s2 = 0.f, s3 = 0.f;
    for (int l = 0; l < 32; l++) {
        const float* row = k + (size_t)(l0 + l) * HD;
        s0 += row[t]; s1 += row[t + 256]; s2 += row[t + 512]; s3 += row[t + 768];
    }
    atomicAdd(&kmsum[t], s0);
    atomicAdd(&kmsum[t + 256], s1);
    atomicAdd(&kmsum[t + 512], s2);
    atomicAdd(&kmsum[t + 768], s3);
}

// K2a: pooled_q[(h*128+m)*64+d] = mean over 64 rows
__global__ void pool_q(const float* __restrict__ q, float* __restrict__ pq) {
    int b = blockIdx.x;
    int h = b >> 7, m = b & 127, d = threadIdx.x;
    const float* base = q + (size_t)m * 64 * HD + h * 64 + d;
    float s = 0.f;
    #pragma unroll 8
    for (int r = 0; r < 64; r++) s += base[(size_t)r * HD];
    pq[(size_t)b * 64 + d] = s * (1.f / 64.f);
}

// K2b: pooled_k[(h*256+n)*64+d] = mean over 32 rows of k minus key-mean
__global__ void pool_k(const float* __restrict__ k, const float* __restrict__ kmsum,
                       float* __restrict__ pk) {
    int b = blockIdx.x;
    int h = b >> 8, n = b & 255, d = threadIdx.x;
    const float* base = k + (size_t)n * 32 * HD + h * 64 + d;
    float s = 0.f;
    #pragma unroll 8
    for (int r = 0; r < 32; r++) s += base[(size_t)r * HD];
    pk[(size_t)b * 64 + d] = s * (1.f / 32.f) - kmsum[h * 64 + d] * (1.f / (float)SEQL);
}

// K3: scores (f64 accum) + top-25 by all-pairs rank (ties: lower index wins,
// matching jax.lax.top_k), output sorted ascending by block index.
__global__ __launch_bounds__(256) void score_topk(const float* __restrict__ pq,
                                                  const float* __restrict__ pk,
                                                  int* __restrict__ lut) {
    __shared__ float pq_s[64];
    __shared__ float s_s[256];
    __shared__ int flag[256];
    int b = blockIdx.x;            // h*128 + m
    int h = b >> 7;
    int t = threadIdx.x;
    if (t < 64) pq_s[t] = pq[(size_t)b * 64 + t];
    __syncthreads();
    const float* kr = pk + ((size_t)h * 256 + t) * 64;
    double acc = 0.0;
    #pragma unroll 8
    for (int d = 0; d < 64; d++) acc += (double)pq_s[d] * (double)kr[d];
    float sc = (float)acc;
    s_s[t] = sc;
    __syncthreads();
    int cnt = 0;
    float si = s_s[t];
    for (int j = 0; j < 256; j++) {
        float sj = s_s[j];
        cnt += (sj > si) || (sj == si && j < t);
    }
    flag[t] = (cnt < TSEL) ? 1 : 0;
    __syncthreads();
    if (cnt < TSEL) {
        int pos = 0;
        for (int j = 0; j < t; j++) pos += flag[j];
        lut[(size_t)b * TSEL + pos] = t;
    }
}

// K5: kvsum[h][d][e] += sum_l k_fm[l][d]*v[l][e]; ksum[h][d] += sum_l k_fm[l][d]
__global__ __launch_bounds__(256) void lin_kv(const float* __restrict__ k,
                                              const float* __restrict__ v,
                                              float* __restrict__ kvsum,
                                              float* __restrict__ ksum) {
    __shared__ float kf[64][68];
    __shared__ float vv[64][68];
    int b = blockIdx.x;
    int h = b >> 7, chunk = b & 127;
    int l0 = chunk * 64;
    int t = threadIdx.x;
    {   // stage 64x64 tiles, float4
        int row = t >> 2, d0 = (t & 3) * 16;
        const float4* ks4 = (const float4*)(k + (size_t)(l0 + row) * HD + h * 64 + d0);
        const float4* vs4 = (const float4*)(v + (size_t)(l0 + row) * HD + h * 64 + d0);
        float4* kd = (float4*)&kf[row][d0];
        float4* vd = (float4*)&vv[row][d0];
        #pragma unroll
        for (int i = 0; i < 4; i++) { kd[i] = ks4[i]; vd[i] = vs4[i]; }
    }
    __syncthreads();
    // softmax k rows in place (wave per 16 rows, lane = d)
    int wv = t >> 6, lane = t & 63;
    for (int rr = 0; rr < 16; rr++) {
        int r = wv * 16 + rr;
        float x = kf[r][lane];
        float mx = x;
        #pragma unroll
        for (int off = 1; off < 64; off <<= 1) mx = fmaxf(mx, __shfl_xor(mx, off, 64));
        float e = __expf(x - mx);
        float sm = e;
        #pragma unroll
        for (int off = 1; off < 64; off <<= 1) sm += __shfl_xor(sm, off, 64);
        kf[r][lane] = e / sm;
    }
    __syncthreads();
    // accumulate outer products: thread = (e, d-group of 16)
    int e_ = t & 63, dg = t >> 6;
    float acc[16];
    #pragma unroll
    for (int j = 0; j < 16; j++) acc[j] = 0.f;
    for (int l = 0; l < 64; l++) {
        float vl = vv[l][e_];
        const float4* k4 = (const float4*)&kf[l][dg * 16];
        float4 a = k4[0], b4 = k4[1], c4 = k4[2], d4 = k4[3];
        acc[0]  += a.x * vl;  acc[1]  += a.y * vl;  acc[2]  += a.z * vl;  acc[3]  += a.w * vl;
        acc[4]  += b4.x * vl; acc[5]  += b4.y * vl; acc[6]  += b4.z * vl; acc[7]  += b4.w * vl;
        acc[8]  += c4.x * vl; acc[9]  += c4.y * vl; acc[10] += c4.z * vl; acc[11] += c4.w * vl;
        acc[12] += d4.x * vl; acc[13] += d4.y * vl; acc[14] += d4.z * vl; acc[15] += d4.w * vl;
    }
    #pragma unroll
    for (int j = 0; j < 16; j++)
        atomicAdd(&kvsum[(size_t)h * 4096 + (dg * 16 + j) * 64 + e_], acc[j]);
    if (t < 64) {
        float s = 0.f;
        for (int l = 0; l < 64; l++) s += kf[l][t];
        atomicAdd(&ksum[h * 64 + t], s);
    }
}

// K6: KW[h][d][dd] = sum_e kvsum[h][d][e] * W[dd][e]
__global__ __launch_bounds__(256) void kw_mul(const float* __restrict__ kvsum,
                                              const float* __restrict__ W,
                                              float* __restrict__ KW) {
    __shared__ float kv[64][65];
    __shared__ float w[64][65];
    int h = blockIdx.x, t = threadIdx.x;
    for (int i = t; i < 4096; i += 256) {
        kv[i >> 6][i & 63] = kvsum[(size_t)h * 4096 + i];
        w[i >> 6][i & 63] = W[i];
    }
    __syncthreads();
    int dd = t & 63, dg = t >> 6;
    #pragma unroll
    for (int j = 0; j < 16; j++) {
        int d = dg * 16 + j;
        float a = 0.f;
        #pragma unroll 8
        for (int e = 0; e < 64; e++) a += kv[d][e] * w[dd][e];
        KW[(size_t)h * 4096 + d * 64 + dd] = a;
    }
}

// K7: block-sparse attention via bf16 MFMA. One block per (h,m), 4 waves.
// Wave w owns q rows [w*16, w*16+16). Per iteration: one 32-row k-block.
// S tiles in C layout (col=lane&15, row=quad*4+reg); P -> LDS -> A-frag; V
// staged transposed so PV B-frag is a contiguous ds_read_b128.
__global__ __launch_bounds__(256) void sparse_attn_mfma(const float* __restrict__ q,
                                                        const float* __restrict__ k,
                                                        const float* __restrict__ v,
                                                        const float* __restrict__ kmsum,
                                                        const int* __restrict__ lut,
                                                        float* __restrict__ out) {
    __shared__ __align__(16) short Kb[2][32][72];   // [kpos][d], stride 72 (144B rows)
    __shared__ __align__(16) short Vtb[2][64][40];  // [d][kpos], stride 40 (80B rows)
    __shared__ __align__(16) short Pl[64][40];      // [qrow][kpos]
    __shared__ float km_s[64];
    __shared__ int lut_s[TSEL];

    int b = blockIdx.x;
    int h = b >> 7, m = b & 127;
    int t = threadIdx.x;
    int w = t >> 6;            // wave 0..3
    int lane = t & 63;
    int l15 = lane & 15;
    int quad = lane >> 4;      // 0..3

    if (t < 64) km_s[t] = kmsum[h * 64 + t] * (1.f / (float)SEQL);
    if (t < TSEL) lut_s[t] = lut[(size_t)b * TSEL + t];
    __syncthreads();

    // Q A-frags (2 K-chunks of 32): A[m=l15][k=quad*8+j]
    bf16x8 qa[2];
    {
        const float* qrow = q + (size_t)(m * 64 + w * 16 + l15) * HD + h * 64;
        #pragma unroll
        for (int kc = 0; kc < 2; kc++) {
            const float4* p4 = (const float4*)(qrow + kc * 32 + quad * 8);
            qa[kc] = cvt8(p4[0], p4[1]);
        }
    }

    // staging thread mapping: 8 elems each of K and V per thread
    int sk = t >> 3;          // kpos 0..31
    int sd = (t & 7) * 8;     // d0

    // initial stage: block lut_s[0] -> buf 0
    {
        int n = lut_s[0];
        const float* kb_ = k + (size_t)(n * 32 + sk) * HD + h * 64 + sd;
        const float* vb_ = v + (size_t)(n * 32 + sk) * HD + h * 64 + sd;
        float4 kx = *(const float4*)kb_, ky = *(const float4*)(kb_ + 4);
        float4 vx = *(const float4*)vb_, vy = *(const float4*)(vb_ + 4);
        kx.x -= km_s[sd + 0]; kx.y -= km_s[sd + 1]; kx.z -= km_s[sd + 2]; kx.w -= km_s[sd + 3];
        ky.x -= km_s[sd + 4]; ky.y -= km_s[sd + 5]; ky.z -= km_s[sd + 6]; ky.w -= km_s[sd + 7];
        *(bf16x8*)&Kb[0][sk][sd] = cvt8(kx, ky);
        short vs[8] = { f2bf(vx.x), f2bf(vx.y), f2bf(vx.z), f2bf(vx.w),
                        f2bf(vy.x), f2bf(vy.y), f2bf(vy.z), f2bf(vy.w) };
        #pragma unroll
        for (int j = 0; j < 8; j++) Vtb[0][sd + j][sk] = vs[j];
    }

    f32x4 O[4];
    #pragma unroll
    for (int dt = 0; dt < 4; dt++) O[dt] = (f32x4){0.f, 0.f, 0.f, 0.f};
    float m_i[4] = {-INFINITY, -INFINITY, -INFINITY, -INFINITY};
    float l_i[4] = {0.f, 0.f, 0.f, 0.f};

    for (int ti = 0; ti < TSEL; ti++) {
        __syncthreads();   // B1: staging(ti) visible; prev PV reads done
        int buf = ti & 1;

        // issue next block's global loads early
        bool hasNext = (ti + 1 < TSEL);
        float4 kx, ky, vx, vy;
        if (hasNext) {
            int n = lut_s[ti + 1];
            const float* kb_ = k + (size_t)(n * 32 + sk) * HD + h * 64 + sd;
            const float* vb_ = v + (size_t)(n * 32 + sk) * HD + h * 64 + sd;
            kx = *(const float4*)kb_; ky = *(const float4*)(kb_ + 4);
            vx = *(const float4*)vb_; vy = *(const float4*)(vb_ + 4);
        }

        // QK^T: S[qrow][kpos], two 16-col tiles
        f32x4 z = (f32x4){0.f, 0.f, 0.f, 0.f};
        bf16x8 b00 = *(const bf16x8*)&Kb[buf][l15][quad * 8];
        bf16x8 b01 = *(const bf16x8*)&Kb[buf][l15][32 + quad * 8];
        bf16x8 b10 = *(const bf16x8*)&Kb[buf][16 + l15][quad * 8];
        bf16x8 b11 = *(const bf16x8*)&Kb[buf][16 + l15][32 + quad * 8];
        f32x4 s0 = __builtin_amdgcn_mfma_f32_16x16x32_bf16(qa[0], b00, z, 0, 0, 0);
        s0 = __builtin_amdgcn_mfma_f32_16x16x32_bf16(qa[1], b01, s0, 0, 0, 0);
        f32x4 s1 = __builtin_amdgcn_mfma_f32_16x16x32_bf16(qa[0], b10, z, 0, 0, 0);
        s1 = __builtin_amdgcn_mfma_f32_16x16x32_bf16(qa[1], b11, s1, 0, 0, 0);

        // online softmax per row (row = w*16 + quad*4 + r)
        float alpha[4];
        #pragma unroll
        for (int r = 0; r < 4; r++) {
            float s0r = s0[r] * 0.125f, s1r = s1[r] * 0.125f;
            float mx = fmaxf(s0r, s1r);
            mx = fmaxf(mx, __shfl_xor(mx, 1, 64));
            mx = fmaxf(mx, __shfl_xor(mx, 2, 64));
            mx = fmaxf(mx, __shfl_xor(mx, 4, 64));
            mx = fmaxf(mx, __shfl_xor(mx, 8, 64));
            float mnew = fmaxf(m_i[r], mx);
            alpha[r] = __expf(m_i[r] - mnew);
            float p0 = __expf(s0r - mnew);
            float p1 = __expf(s1r - mnew);
            float sm = p0 + p1;
            sm += __shfl_xor(sm, 1, 64);
            sm += __shfl_xor(sm, 2, 64);
            sm += __shfl_xor(sm, 4, 64);
            sm += __shfl_xor(sm, 8, 64);
            l_i[r] = l_i[r] * alpha[r] + sm;
            m_i[r] = mnew;
            s0[r] = p0; s1[r] = p1;
        }
        // write P (bf16) to LDS
        int prow = w * 16 + quad * 4;
        #pragma unroll
        for (int r = 0; r < 4; r++) {
            Pl[prow + r][l15] = f2bf(s0[r]);
            Pl[prow + r][16 + l15] = f2bf(s1[r]);
        }
        // rescale O
        #pragma unroll
        for (int dt = 0; dt < 4; dt++) {
            #pragma unroll
            for (int r = 0; r < 4; r++) O[dt][r] *= alpha[r];
        }
        // stage next block into the other buffer
        if (hasNext) {
            int bn = buf ^ 1;
            kx.x -= km_s[sd + 0]; kx.y -= km_s[sd + 1]; kx.z -= km_s[sd + 2]; kx.w -= km_s[sd + 3];
            ky.x -= km_s[sd + 4]; ky.y -= km_s[sd + 5]; ky.z -= km_s[sd + 6]; ky.w -= km_s[sd + 7];
            *(bf16x8*)&Kb[bn][sk][sd] = cvt8(kx, ky);
            short vs[8] = { f2bf(vx.x), f2bf(vx.y), f2bf(vx.z), f2bf(vx.w),
                            f2bf(vy.x), f2bf(vy.y), f2bf(vy.z), f2bf(vy.w) };
            #pragma unroll
            for (int j = 0; j < 8; j++) Vtb[bn][sd + j][sk] = vs[j];
        }
        __syncthreads();   // B2: P visible
        // PV: O[qrow][dcol] += P · V
        bf16x8 pa = *(const bf16x8*)&Pl[w * 16 + l15][quad * 8];
        #pragma unroll
        for (int dt = 0; dt < 4; dt++) {
            bf16x8 vb = *(const bf16x8*)&Vtb[buf][dt * 16 + l15][quad * 8];
            O[dt] = __builtin_amdgcn_mfma_f32_16x16x32_bf16(pa, vb, O[dt], 0, 0, 0);
        }
    }

    float inv[4];
    #pragma unroll
    for (int r = 0; r < 4; r++) inv[r] = 1.f / l_i[r];
    #pragma unroll
    for (int dt = 0; dt < 4; dt++) {
        #pragma unroll
        for (int r = 0; r < 4; r++) {
            int row = w * 16 + quad * 4 + r;
            out[(size_t)(m * 64 + row) * HD + h * 64 + dt * 16 + l15] = O[dt][r] * inv[r];
        }
    }
}

// K8: linear-branch output: out[l][h][dd] += (q_fm . KW[h][:,dd]) / denom + b[dd]
__global__ __launch_bounds__(256) void lin_out(const float* __restrict__ q,
                                               const float* __restrict__ KW,
                                               const float* __restrict__ ksum,
                                               const float* __restrict__ bproj,
                                               float* __restrict__ out) {
    __shared__ float qf[64][65];
    __shared__ float kwl[64][68];
    __shared__ float ks_s[64];
    __shared__ float b_s[64];
    __shared__ float denom_s[64];
    int b = blockIdx.x;
    int h = b >> 7, chunk = b & 127;
    int l0 = chunk * 64;
    int t = threadIdx.x;
    if (t < 64) { ks_s[t] = ksum[h * 64 + t]; b_s[t] = bproj[t]; }
    {   // stage q rows and KW
        int row = t >> 2, d0 = (t & 3) * 16;
        const float* src = q + (size_t)(l0 + row) * HD + h * 64 + d0;
        #pragma unroll
        for (int j = 0; j < 16; j++) qf[row][d0 + j] = src[j];
        const float4* ks4 = (const float4*)(KW + (size_t)h * 4096 + row * 64 + d0);
        float4* kd = (float4*)&kwl[row][d0];
        #pragma unroll
        for (int i = 0; i < 4; i++) kd[i] = ks4[i];
    }
    __syncthreads();
    int wv = t >> 6, lane = t & 63;
    for (int rr = 0; rr < 16; rr++) {   // softmax q rows + denom
        int r = wv * 16 + rr;
        float x = qf[r][lane];
        float mx = x;
        #pragma unroll
        for (int off = 1; off < 64; off <<= 1) mx = fmaxf(mx, __shfl_xor(mx, off, 64));
        float e = __expf(x - mx);
        float sm = e;
        #pragma unroll
        for (int off = 1; off < 64; off <<= 1) sm += __shfl_xor(sm, off, 64);
        float fmv = e / sm;
        qf[r][lane] = fmv;
        float dp = fmv * ks_s[lane];
        #pragma unroll
        for (int off = 1; off < 64; off <<= 1) dp += __shfl_xor(dp, off, 64);
        if (lane == 0) denom_s[r] = dp + 1e-6f;
    }
    __syncthreads();
    // matvec: wave wv owns dd-chunk [wv*16, wv*16+16), lane = seq row
    float acc[16];
    #pragma unroll
    for (int j = 0; j < 16; j++) acc[j] = 0.f;
    for (int d = 0; d < 64; d++) {
        float qv = qf[lane][d];
        const float4* k4 = (const float4*)&kwl[d][wv * 16];
        float4 a = k4[0], b4 = k4[1], c4 = k4[2], d4 = k4[3];
        acc[0]  += qv * a.x;  acc[1]  += qv * a.y;  acc[2]  += qv * a.z;  acc[3]  += qv * a.w;
        acc[4]  += qv * b4.x; acc[5]  += qv * b4.y; acc[6]  += qv * b4.z; acc[7]  += qv * b4.w;
        acc[8]  += qv * c4.x; acc[9]  += qv * c4.y; acc[10] += qv * c4.z; acc[11] += qv * c4.w;
        acc[12] += qv * d4.x; acc[13] += qv * d4.y; acc[14] += qv * d4.z; acc[15] += qv * d4.w;
    }
    float invd = 1.f / denom_s[lane];
    float* dst = out + (size_t)(l0 + lane) * HD + h * 64 + wv * 16;
    #pragma unroll
    for (int j4 = 0; j4 < 4; j4++) {
        float4 o = *(float4*)&dst[j4 * 4];
        o.x += acc[j4 * 4 + 0] * invd + b_s[wv * 16 + j4 * 4 + 0];
        o.y += acc[j4 * 4 + 1] * invd + b_s[wv * 16 + j4 * 4 + 1];
        o.z += acc[j4 * 4 + 2] * invd + b_s[wv * 16 + j4 * 4 + 2];
        o.w += acc[j4 * 4 + 3] * invd + b_s[wv * 16 + j4 * 4 + 3];
        *(float4*)&dst[j4 * 4] = o;
    }
}

extern "C" void kernel_launch(void* const* d_in, const int* in_sizes, int n_in,
                              void* d_out, int out_size, void* d_ws, size_t ws_size,
                              hipStream_t stream) {
    const float* q  = (const float*)d_in[0];
    const float* k  = (const float*)d_in[1];
    const float* v  = (const float*)d_in[2];
    const float* W  = (const float*)d_in[3];
    const float* bp = (const float*)d_in[4];
    float* out = (float*)d_out;
    float* ws = (float*)d_ws;

    float* kmsum = ws + OFF_KM;
    float* kvsum = ws + OFF_KVSUM;
    float* ksum  = ws + OFF_KSUM;
    float* pq    = ws + OFF_PQ;
    float* pk    = ws + OFF_PK;
    int*   lut   = (int*)(ws + OFF_LUT);
    float* KW    = ws + OFF_KW;

    hipMemsetAsync(ws, 0, OFF_ZEND * sizeof(float), stream);
    k_mean<<<256, 256, 0, stream>>>(k, kmsum);
    pool_q<<<2048, 64, 0, stream>>>(q, pq);
    pool_k<<<4096, 64, 0, stream>>>(k, kmsum, pk);
    score_topk<<<2048, 256, 0, stream>>>(pq, pk, lut);
    lin_kv<<<2048, 256, 0, stream>>>(k, v, kvsum, ksum);
    kw_mul<<<16, 256, 0, stream>>>(kvsum, W, KW);
    sparse_attn_mfma<<<2048, 256, 0, stream>>>(q, k, v, kmsum, lut, out);
    lin_out<<<2048, 256, 0, stream>>>(q, KW, ksum, bp, out);
}

// Round 3
// 383.684 us; speedup vs baseline: 2.5177x; 1.1948x over previous
//
#include <hip/hip_runtime.h>
#include <math.h>

#define SEQL 8192
#define NH 16
#define HD 1024           // NH * 64
#define NM 128            // SEQL / 64
#define NN 256            // SEQL / 32
#define TSEL 25

// ---- workspace layout (float offsets) ----
#define OFF_KM     0                         // 1024  (zeroed, atomics)
#define OFF_KVSUM  1024                      // 16*4096 (zeroed, atomics)
#define OFF_KSUM   (1024 + 16*4096)          // 1024  (zeroed, atomics)
#define OFF_ZEND   (OFF_KSUM + 1024)
#define OFF_PQ     OFF_ZEND                  // 16*128*64
#define OFF_PK     (OFF_PQ + 16*128*64)      // 16*256*64
#define OFF_LUT    (OFF_PK + 16*256*64)      // 16*128*25 ints
#define OFF_KW     (OFF_LUT + 16*128*25)     // 16*4096
#define OFF_KSWZ   (OFF_KW + 16*4096)        // 16 MB of bf16 K (swizzled), as shorts
// vswz follows kswz: another 16*256*2048 shorts

typedef __attribute__((ext_vector_type(8))) short bf16x8;
typedef __attribute__((ext_vector_type(4))) short s16x4;
typedef __attribute__((ext_vector_type(4))) float f32x4;

static __device__ inline short f2bf(float f) {
    union { float f; unsigned u; } c; c.f = f;
    unsigned r = (c.u + 0x7FFFu + ((c.u >> 16) & 1u)) >> 16;
    return (short)r;
}
static __device__ inline bf16x8 cvt8(float4 a, float4 b) {
    bf16x8 r;
    r[0] = f2bf(a.x); r[1] = f2bf(a.y); r[2] = f2bf(a.z); r[3] = f2bf(a.w);
    r[4] = f2bf(b.x); r[5] = f2bf(b.y); r[6] = f2bf(b.z); r[7] = f2bf(b.w);
    return r;
}
static __device__ inline void load_lds16(const void* g, void* l) {
    __builtin_amdgcn_global_load_lds((const __attribute__((address_space(1))) unsigned int*)g,
                                     (__attribute__((address_space(3))) unsigned int*)l,
                                     16, 0, 0);
}

// K1: km_sum[h*64+d] = sum_l k[l][h][d]   (used by routing/pool_k only)
__global__ void k_mean(const float* __restrict__ k, float* __restrict__ kmsum) {
    int b = blockIdx.x, t = threadIdx.x;
    int l0 = b * 32;
    float s0 = 0.f, s1 = 0.f, s2 = 0.f, s3 = 0.f;
    for (int l = 0; l < 32; l++) {
        const float* row = k + (size_t)(l0 + l) * HD;
        s0 += row[t]; s1 += row[t + 256]; s2 += row[t + 512]; s3 += row[t + 768];
    }
    atomicAdd(&kmsum[t], s0);
    atomicAdd(&kmsum[t + 256], s1);
    atomicAdd(&kmsum[t + 512], s2);
    atomicAdd(&kmsum[t + 768], s3);
}

// K2a: pooled_q
__global__ void pool_q(const float* __restrict__ q, float* __restrict__ pq) {
    int b = blockIdx.x;
    int h = b >> 7, m = b & 127, d = threadIdx.x;
    const float* base = q + (size_t)m * 64 * HD + h * 64 + d;
    float s = 0.f;
    #pragma unroll 8
    for (int r = 0; r < 64; r++) s += base[(size_t)r * HD];
    pq[(size_t)b * 64 + d] = s * (1.f / 64.f);
}

// K2b: pooled_k (centered — centering matters for routing)
__global__ void pool_k(const float* __restrict__ k, const float* __restrict__ kmsum,
                       float* __restrict__ pk) {
    int b = blockIdx.x;
    int h = b >> 8, n = b & 255, d = threadIdx.x;
    const float* base = k + (size_t)n * 32 * HD + h * 64 + d;
    float s = 0.f;
    #pragma unroll 8
    for (int r = 0; r < 32; r++) s += base[(size_t)r * HD];
    pk[(size_t)b * 64 + d] = s * (1.f / 32.f) - kmsum[h * 64 + d] * (1.f / (float)SEQL);
}

// K3: scores (f64 accum) + top-25 rank select (jax tie semantics), sorted asc.
__global__ __launch_bounds__(256) void score_topk(const float* __restrict__ pq,
                                                  const float* __restrict__ pk,
                                                  int* __restrict__ lut) {
    __shared__ float pq_s[64];
    __shared__ float s_s[256];
    __shared__ int flag[256];
    int b = blockIdx.x;            // h*128 + m
    int h = b >> 7;
    int t = threadIdx.x;
    if (t < 64) pq_s[t] = pq[(size_t)b * 64 + t];
    __syncthreads();
    const float* kr = pk + ((size_t)h * 256 + t) * 64;
    double acc = 0.0;
    #pragma unroll 8
    for (int d = 0; d < 64; d++) acc += (double)pq_s[d] * (double)kr[d];
    float sc = (float)acc;
    s_s[t] = sc;
    __syncthreads();
    int cnt = 0;
    float si = s_s[t];
    for (int j = 0; j < 256; j++) {
        float sj = s_s[j];
        cnt += (sj > si) || (sj == si && j < t);
    }
    flag[t] = (cnt < TSEL) ? 1 : 0;
    __syncthreads();
    if (cnt < TSEL) {
        int pos = 0;
        for (int j = 0; j < t; j++) pos += flag[j];
        lut[(size_t)b * TSEL + pos] = t;
    }
}

// K4: pre-pass — per (h,n): K tile -> bf16 swizzled; V tile -> V^T bf16 swizzled.
// K chunk (r,ch) [16B] stored at flat chunk r*8 + (ch ^ (r&7)).
// V^T chunk (d,c) [16B] stored at flat chunk d*4 + (c ^ ((d>>1)&3)).
__global__ __launch_bounds__(256) void prep_kv(const float* __restrict__ k,
                                               const float* __restrict__ v,
                                               short* __restrict__ kswz,
                                               short* __restrict__ vswz) {
    int b = blockIdx.x;            // h*256 + n
    int h = b >> 8, n = b & 255;
    int t = threadIdx.x;
    {   // K: thread = (r = t>>3, ch = t&7)
        int r = t >> 3, ch = t & 7;
        const float* src = k + (size_t)(n * 32 + r) * HD + h * 64 + ch * 8;
        bf16x8 val = cvt8(*(const float4*)src, *(const float4*)(src + 4));
        int f = r * 8 + (ch ^ (r & 7));
        *(bf16x8*)(kswz + (size_t)b * 2048 + f * 8) = val;
    }
    {   // V^T: thread = (c = t>>6, d = t&63); gathers 8 kpos for one d
        int c = t >> 6, d = t & 63;
        const float* src = v + (size_t)(n * 32 + c * 8) * HD + h * 64 + d;
        bf16x8 val;
        #pragma unroll
        for (int j = 0; j < 8; j++) val[j] = f2bf(src[(size_t)j * HD]);
        int f = d * 4 + (c ^ ((d >> 1) & 3));
        *(bf16x8*)(vswz + (size_t)b * 2048 + f * 8) = val;
    }
}

// K5: kvsum += k_fm^T v ; ksum += col-sums. 512 blocks x 4 sub-tiles (atomics /4).
__global__ __launch_bounds__(256) void lin_kv(const float* __restrict__ k,
                                              const float* __restrict__ v,
                                              float* __restrict__ kvsum,
                                              float* __restrict__ ksum) {
    __shared__ float kf[64][68];
    __shared__ float vv[64][68];
    int b = blockIdx.x;            // h*32 + chunk
    int h = b >> 5, chunk = b & 31;
    int t = threadIdx.x;
    int e_ = t & 63, dg = t >> 6;
    int wv = t >> 6, lane = t & 63;
    float acc[16];
    #pragma unroll
    for (int j = 0; j < 16; j++) acc[j] = 0.f;
    float ks_acc = 0.f;
    for (int st = 0; st < 4; st++) {
        int l0 = chunk * 256 + st * 64;
        __syncthreads();   // protect kf/vv reuse
        {   // stage
            int row = t >> 2, d0 = (t & 3) * 16;
            const float4* ks4 = (const float4*)(k + (size_t)(l0 + row) * HD + h * 64 + d0);
            const float4* vs4 = (const float4*)(v + (size_t)(l0 + row) * HD + h * 64 + d0);
            float4* kd = (float4*)&kf[row][d0];
            float4* vd = (float4*)&vv[row][d0];
            #pragma unroll
            for (int i = 0; i < 4; i++) { kd[i] = ks4[i]; vd[i] = vs4[i]; }
        }
        __syncthreads();
        for (int rr = 0; rr < 16; rr++) {   // softmax k rows in place
            int r = wv * 16 + rr;
            float x = kf[r][lane];
            float mx = x;
            #pragma unroll
            for (int off = 1; off < 64; off <<= 1) mx = fmaxf(mx, __shfl_xor(mx, off, 64));
            float e = __expf(x - mx);
            float sm = e;
            #pragma unroll
            for (int off = 1; off < 64; off <<= 1) sm += __shfl_xor(sm, off, 64);
            kf[r][lane] = e / sm;
        }
        __syncthreads();
        for (int l = 0; l < 64; l++) {
            float vl = vv[l][e_];
            const float4* k4 = (const float4*)&kf[l][dg * 16];
            float4 a = k4[0], b4 = k4[1], c4 = k4[2], d4 = k4[3];
            acc[0]  += a.x * vl;  acc[1]  += a.y * vl;  acc[2]  += a.z * vl;  acc[3]  += a.w * vl;
            acc[4]  += b4.x * vl; acc[5]  += b4.y * vl; acc[6]  += b4.z * vl; acc[7]  += b4.w * vl;
            acc[8]  += c4.x * vl; acc[9]  += c4.y * vl; acc[10] += c4.z * vl; acc[11] += c4.w * vl;
            acc[12] += d4.x * vl; acc[13] += d4.y * vl; acc[14] += d4.z * vl; acc[15] += d4.w * vl;
        }
        if (t < 64) {
            float s = 0.f;
            for (int l = 0; l < 64; l++) s += kf[l][t];
            ks_acc += s;
        }
    }
    #pragma unroll
    for (int j = 0; j < 16; j++)
        atomicAdd(&kvsum[(size_t)h * 4096 + (dg * 16 + j) * 64 + e_], acc[j]);
    if (t < 64) atomicAdd(&ksum[h * 64 + t], ks_acc);
}

// K6: KW[h][d][dd] = sum_e kvsum[h][d][e] * W[dd][e]
__global__ __launch_bounds__(256) void kw_mul(const float* __restrict__ kvsum,
                                              const float* __restrict__ W,
                                              float* __restrict__ KW) {
    __shared__ float kv[64][65];
    __shared__ float w[64][65];
    int h = blockIdx.x, t = threadIdx.x;
    for (int i = t; i < 4096; i += 256) {
        kv[i >> 6][i & 63] = kvsum[(size_t)h * 4096 + i];
        w[i >> 6][i & 63] = W[i];
    }
    __syncthreads();
    int dd = t & 63, dg = t >> 6;
    #pragma unroll
    for (int j = 0; j < 16; j++) {
        int d = dg * 16 + j;
        float a = 0.f;
        #pragma unroll 8
        for (int e = 0; e < 64; e++) a += kv[d][e] * w[dd][e];
        KW[(size_t)h * 4096 + d * 64 + dd] = a;
    }
}

// K7: block-sparse attention, operand-swapped MFMA (S^T / O^T), lane-resident
// softmax state, no centering (shift-invariant), no running max (|s|*scale <~6),
// staging via global_load_lds from pre-swizzled bf16, lgkm-only mid barrier.
__global__ __launch_bounds__(256) void sparse_attn_mfma(const float* __restrict__ q,
                                                        const short* __restrict__ kswz,
                                                        const short* __restrict__ vswz,
                                                        const int* __restrict__ lut,
                                                        float* __restrict__ out) {
    __shared__ __align__(16) short Kb[2][2048];
    __shared__ __align__(16) short Vb[2][2048];
    __shared__ __align__(16) short Pl[64][40];
    __shared__ int lut_s[TSEL];

    int b = blockIdx.x;
    int x = b & 7, jj = b >> 3;
    int h = x * 2 + (jj >> 7);       // XCD-affine: blocks on one XCD share h
    int m = jj & 127;
    int t = threadIdx.x;
    int lane = t & 63, w = t >> 6;
    int l15 = lane & 15, quad = lane >> 4;

    if (t < TSEL) lut_s[t] = lut[(size_t)(h * 128 + m) * TSEL + t];
    __syncthreads();

    // Q fragment (used as MFMA B operand): B[k=d(quad*8+j)][n=qrow(l15)]
    bf16x8 qa[2];
    {
        const float* qrow = q + (size_t)(m * 64 + w * 16 + l15) * HD + h * 64;
        #pragma unroll
        for (int kc = 0; kc < 2; kc++)
            qa[kc] = cvt8(*(const float4*)(qrow + kc * 32 + quad * 8),
                          *(const float4*)(qrow + kc * 32 + quad * 8 + 4));
    }

    // prologue: stage block 0 into buf 0 (1KB per wave per instr, linear)
    {
        size_t base = (size_t)(h * 256 + lut_s[0]) * 2048;
        load_lds16(kswz + base + t * 8, &Kb[0][t * 8]);
        load_lds16(vswz + base + t * 8, &Vb[0][t * 8]);
    }

    f32x4 O[4];
    #pragma unroll
    for (int dt = 0; dt < 4; dt++) O[dt] = (f32x4){0.f, 0.f, 0.f, 0.f};
    float l_i = 0.f;
    const f32x4 z = (f32x4){0.f, 0.f, 0.f, 0.f};

    for (int ti = 0; ti < TSEL; ti++) {
        __syncthreads();              // B1: staging for ti complete (vmcnt drain)
        int buf = ti & 1;
        if (ti + 1 < TSEL) {          // prefetch ti+1 (stays in flight across B2)
            size_t base = (size_t)(h * 256 + lut_s[ti + 1]) * 2048;
            load_lds16(kswz + base + t * 8, &Kb[buf ^ 1][t * 8]);
            load_lds16(vswz + base + t * 8, &Vb[buf ^ 1][t * 8]);
        }
        // S^T = K · Q^T : A-frag = K rows (kpos), swizzled chunks
        int r0 = l15, r1 = 16 + l15;
        bf16x8 a00 = *(const bf16x8*)&Kb[buf][(r0 * 8 + (quad ^ (r0 & 7))) * 8];
        bf16x8 a01 = *(const bf16x8*)&Kb[buf][(r0 * 8 + ((4 + quad) ^ (r0 & 7))) * 8];
        bf16x8 a10 = *(const bf16x8*)&Kb[buf][(r1 * 8 + (quad ^ (r1 & 7))) * 8];
        bf16x8 a11 = *(const bf16x8*)&Kb[buf][(r1 * 8 + ((4 + quad) ^ (r1 & 7))) * 8];
        f32x4 s0 = __builtin_amdgcn_mfma_f32_16x16x32_bf16(a00, qa[0], z, 0, 0, 0);
        s0 = __builtin_amdgcn_mfma_f32_16x16x32_bf16(a01, qa[1], s0, 0, 0, 0);
        f32x4 s1 = __builtin_amdgcn_mfma_f32_16x16x32_bf16(a10, qa[0], z, 0, 0, 0);
        s1 = __builtin_amdgcn_mfma_f32_16x16x32_bf16(a11, qa[1], s1, 0, 0, 0);

        // p = exp(s*scale), fixed max. lane holds kpos {quad*4+r, 16+quad*4+r} of qrow l15.
        float p0[4], p1[4];
        float lsum = 0.f;
        #pragma unroll
        for (int r = 0; r < 4; r++) {
            p0[r] = __expf(s0[r] * 0.125f);
            p1[r] = __expf(s1[r] * 0.125f);
            lsum += p0[r] + p1[r];
        }
        lsum += __shfl_xor(lsum, 16, 64);
        lsum += __shfl_xor(lsum, 32, 64);
        l_i += lsum;

        s16x4 pk0, pk1;
        #pragma unroll
        for (int r = 0; r < 4; r++) { pk0[r] = f2bf(p0[r]); pk1[r] = f2bf(p1[r]); }
        *(s16x4*)&Pl[w * 16 + l15][quad * 4] = pk0;
        *(s16x4*)&Pl[w * 16 + l15][16 + quad * 4] = pk1;

        // B2: LDS-only barrier — async prefetch stays in flight
        asm volatile("s_waitcnt lgkmcnt(0)\n\ts_barrier" ::: "memory");

        // O^T += V^T · P^T
        bf16x8 pb = *(const bf16x8*)&Pl[w * 16 + l15][quad * 8];
        #pragma unroll
        for (int dt = 0; dt < 4; dt++) {
            int d = dt * 16 + l15;
            bf16x8 va = *(const bf16x8*)&Vb[buf][(d * 4 + (quad ^ ((d >> 1) & 3))) * 8];
            O[dt] = __builtin_amdgcn_mfma_f32_16x16x32_bf16(va, pb, O[dt], 0, 0, 0);
        }
    }

    float inv = 1.f / l_i;
    float* dst = out + (size_t)(m * 64 + w * 16 + l15) * HD + h * 64;
    #pragma unroll
    for (int dt = 0; dt < 4; dt++) {
        float4 o = make_float4(O[dt][0] * inv, O[dt][1] * inv, O[dt][2] * inv, O[dt][3] * inv);
        *(float4*)(dst + dt * 16 + quad * 4) = o;
    }
}

// K8: linear-branch output (adds into out)
__global__ __launch_bounds__(256) void lin_out(const float* __restrict__ q,
                                               const float* __restrict__ KW,
                                               const float* __restrict__ ksum,
                                               const float* __restrict__ bproj,
                                               float* __restrict__ out) {
    __shared__ float qf[64][65];
    __shared__ float kwl[64][68];
    __shared__ float ks_s[64];
    __shared__ float b_s[64];
    __shared__ float denom_s[64];
    int b = blockIdx.x;
    int h = b >> 7, chunk = b & 127;
    int l0 = chunk * 64;
    int t = threadIdx.x;
    if (t < 64) { ks_s[t] = ksum[h * 64 + t]; b_s[t] = bproj[t]; }
    {
        int row = t >> 2, d0 = (t & 3) * 16;
        const float* src = q + (size_t)(l0 + row) * HD + h * 64 + d0;
        #pragma unroll
        for (int j = 0; j < 16; j++) qf[row][d0 + j] = src[j];
        const float4* ks4 = (const float4*)(KW + (size_t)h * 4096 + row * 64 + d0);
        float4* kd = (float4*)&kwl[row][d0];
        #pragma unroll
        for (int i = 0; i < 4; i++) kd[i] = ks4[i];
    }
    __syncthreads();
    int wv = t >> 6, lane = t & 63;
    for (int rr = 0; rr < 16; rr++) {
        int r = wv * 16 + rr;
        float x = qf[r][lane];
        float mx = x;
        #pragma unroll
        for (int off = 1; off < 64; off <<= 1) mx = fmaxf(mx, __shfl_xor(mx, off, 64));
        float e = __expf(x - mx);
        float sm = e;
        #pragma unroll
        for (int off = 1; off < 64; off <<= 1) sm += __shfl_xor(sm, off, 64);
        float fmv = e / sm;
        qf[r][lane] = fmv;
        float dp = fmv * ks_s[lane];
        #pragma unroll
        for (int off = 1; off < 64; off <<= 1) dp += __shfl_xor(dp, off, 64);
        if (lane == 0) denom_s[r] = dp + 1e-6f;
    }
    __syncthreads();
    float acc[16];
    #pragma unroll
    for (int j = 0; j < 16; j++) acc[j] = 0.f;
    for (int d = 0; d < 64; d++) {
        float qv = qf[lane][d];
        const float4* k4 = (const float4*)&kwl[d][wv * 16];
        float4 a = k4[0], b4 = k4[1], c4 = k4[2], d4 = k4[3];
        acc[0]  += qv * a.x;  acc[1]  += qv * a.y;  acc[2]  += qv * a.z;  acc[3]  += qv * a.w;
        acc[4]  += qv * b4.x; acc[5]  += qv * b4.y; acc[6]  += qv * b4.z; acc[7]  += qv * b4.w;
        acc[8]  += qv * c4.x; acc[9]  += qv * c4.y; acc[10] += qv * c4.z; acc[11] += qv * c4.w;
        acc[12] += qv * d4.x; acc[13] += qv * d4.y; acc[14] += qv * d4.z; acc[15] += qv * d4.w;
    }
    float invd = 1.f / denom_s[lane];
    float* dst = out + (size_t)(l0 + lane) * HD + h * 64 + wv * 16;
    #pragma unroll
    for (int j4 = 0; j4 < 4; j4++) {
        float4 o = *(float4*)&dst[j4 * 4];
        o.x += acc[j4 * 4 + 0] * invd + b_s[wv * 16 + j4 * 4 + 0];
        o.y += acc[j4 * 4 + 1] * invd + b_s[wv * 16 + j4 * 4 + 1];
        o.z += acc[j4 * 4 + 2] * invd + b_s[wv * 16 + j4 * 4 + 2];
        o.w += acc[j4 * 4 + 3] * invd + b_s[wv * 16 + j4 * 4 + 3];
        *(float4*)&dst[j4 * 4] = o;
    }
}

extern "C" void kernel_launch(void* const* d_in, const int* in_sizes, int n_in,
                              void* d_out, int out_size, void* d_ws, size_t ws_size,
                              hipStream_t stream) {
    const float* q  = (const float*)d_in[0];
    const float* k  = (const float*)d_in[1];
    const float* v  = (const float*)d_in[2];
    const float* W  = (const float*)d_in[3];
    const float* bp = (const float*)d_in[4];
    float* out = (float*)d_out;
    float* ws = (float*)d_ws;

    float* kmsum = ws + OFF_KM;
    float* kvsum = ws + OFF_KVSUM;
    float* ksum  = ws + OFF_KSUM;
    float* pq    = ws + OFF_PQ;
    float* pk    = ws + OFF_PK;
    int*   lut   = (int*)(ws + OFF_LUT);
    float* KW    = ws + OFF_KW;
    short* kswz  = (short*)(ws + OFF_KSWZ);
    short* vswz  = kswz + (size_t)16 * 256 * 2048;

    hipMemsetAsync(ws, 0, OFF_ZEND * sizeof(float), stream);
    k_mean<<<256, 256, 0, stream>>>(k, kmsum);
    prep_kv<<<4096, 256, 0, stream>>>(k, v, kswz, vswz);
    pool_q<<<2048, 64, 0, stream>>>(q, pq);
    pool_k<<<4096, 64, 0, stream>>>(k, kmsum, pk);
    score_topk<<<2048, 256, 0, stream>>>(pq, pk, lut);
    lin_kv<<<512, 256, 0, stream>>>(k, v, kvsum, ksum);
    kw_mul<<<16, 256, 0, stream>>>(kvsum, W, KW);
    sparse_attn_mfma<<<2048, 256, 0, stream>>>(q, kswz, vswz, lut, out);
    lin_out<<<2048, 256, 0, stream>>>(q, KW, ksum, bp, out);
}

// Round 5
// 287.677 us; speedup vs baseline: 3.3579x; 1.3337x over previous
//
#include <hip/hip_runtime.h>
#include <math.h>

#define SEQL 8192
#define NH 16
#define HD 1024           // NH * 64
#define TSEL 25

// ---- workspace layout (float offsets) ----
// kvpart: 4 partials x 16h x 4096, zeroed. pq/lut OVERLAY kvpart (written only
// after kw_mul consumed it). pk is outside (written early by prep_kv).
#define OFF_KVPART 0                         // 4*16*4096 = 262144 (zeroed)
#define OFF_KSUM   262144                    // 1024 (zeroed)
#define OFF_ZEND   263168
#define OFF_PK     263168                    // 16*256*64 = 262144
#define OFF_KWT    525312                    // 16*4096 shorts = 32768 floats
#define OFF_KSWZ   558080                    // 16*256*2048 shorts
#define OFF_PQ     0                         // overlays kvpart (16*128*64)
#define OFF_LUT    131072                    // overlays kvpart (16*128*25 ints)

typedef __attribute__((ext_vector_type(8))) short bf16x8;
typedef __attribute__((ext_vector_type(4))) float f32x4;

static __device__ inline short f2bf(float f) {
    union { float f; unsigned u; } c; c.f = f;
    unsigned r = (c.u + 0x7FFFu + ((c.u >> 16) & 1u)) >> 16;
    return (short)r;
}
static __device__ inline bf16x8 cvt8(float4 a, float4 b) {
    bf16x8 r;
    r[0] = f2bf(a.x); r[1] = f2bf(a.y); r[2] = f2bf(a.z); r[3] = f2bf(a.w);
    r[4] = f2bf(b.x); r[5] = f2bf(b.y); r[6] = f2bf(b.z); r[7] = f2bf(b.w);
    return r;
}
static __device__ inline void load_lds16(const void* g, void* l) {
    __builtin_amdgcn_global_load_lds((const __attribute__((address_space(1))) unsigned int*)g,
                                     (__attribute__((address_space(3))) unsigned int*)l,
                                     16, 0, 0);
}

// K1: pre-pass — per (h,n): K tile -> bf16 swizzled; V tile -> V^T bf16 swizzled;
// fused pooled_k (raw block mean — centering dropped: rank-invariant for top-k).
__global__ __launch_bounds__(256) void prep_kv(const float* __restrict__ k,
                                               const float* __restrict__ v,
                                               short* __restrict__ kswz,
                                               short* __restrict__ vswz,
                                               float* __restrict__ pk) {
    __shared__ float pcol[4][64];
    int b = blockIdx.x;            // h*256 + n
    int h = b >> 8, n = b & 255;
    int t = threadIdx.x;
    {   // K: thread = (r = t>>3, ch = t&7); lane bits [5:3]=r%8, [2:0]=ch
        int r = t >> 3, ch = t & 7;
        const float* src = k + (size_t)(n * 32 + r) * HD + h * 64 + ch * 8;
        float4 f0 = *(const float4*)src, f1 = *(const float4*)(src + 4);
        int f = r * 8 + (ch ^ (r & 7));
        *(bf16x8*)(kswz + (size_t)b * 2048 + f * 8) = cvt8(f0, f1);
        // column partial sums over this wave's 8 rows (reduce over lane bits 3,4,5)
        float s[8] = { f0.x, f0.y, f0.z, f0.w, f1.x, f1.y, f1.z, f1.w };
        #pragma unroll
        for (int j = 0; j < 8; j++) {
            s[j] += __shfl_xor(s[j], 8, 64);
            s[j] += __shfl_xor(s[j], 16, 64);
            s[j] += __shfl_xor(s[j], 32, 64);
        }
        if ((t & 63) < 8) {
            #pragma unroll
            for (int j = 0; j < 8; j++) pcol[t >> 6][(t & 7) * 8 + j] = s[j];
        }
    }
    {   // V^T: thread = (c = t>>6, d = t&63); gathers 8 kpos for one d
        int c = t >> 6, d = t & 63;
        const float* src = v + (size_t)(n * 32 + c * 8) * HD + h * 64 + d;
        bf16x8 val;
        #pragma unroll
        for (int j = 0; j < 8; j++) val[j] = f2bf(src[(size_t)j * HD]);
        int f = d * 4 + (c ^ ((d >> 1) & 3));
        *(bf16x8*)(vswz + (size_t)b * 2048 + f * 8) = val;
    }
    __syncthreads();
    if (t < 64)
        pk[(size_t)b * 64 + t] =
            (pcol[0][t] + pcol[1][t] + pcol[2][t] + pcol[3][t]) * (1.f / 32.f);
}

// K2: pooled_q
__global__ void pool_q(const float* __restrict__ q, float* __restrict__ pq) {
    int b = blockIdx.x;
    int h = b >> 7, m = b & 127, d = threadIdx.x;
    const float* base = q + (size_t)m * 64 * HD + h * 64 + d;
    float s = 0.f;
    #pragma unroll 8
    for (int r = 0; r < 64; r++) s += base[(size_t)r * HD];
    pq[(size_t)b * 64 + d] = s * (1.f / 64.f);
}

// K3: scores (f64 accum, uncentered — per-m constant shift doesn't change rank)
// + top-25 rank select (jax tie semantics), sorted asc.
__global__ __launch_bounds__(256) void score_topk(const float* __restrict__ pq,
                                                  const float* __restrict__ pk,
                                                  int* __restrict__ lut) {
    __shared__ float pq_s[64];
    __shared__ float s_s[256];
    __shared__ int flag[256];
    int b = blockIdx.x;            // h*128 + m
    int h = b >> 7;
    int t = threadIdx.x;
    if (t < 64) pq_s[t] = pq[(size_t)b * 64 + t];
    __syncthreads();
    const float* kr = pk + ((size_t)h * 256 + t) * 64;
    double acc = 0.0;
    #pragma unroll 8
    for (int d = 0; d < 64; d++) acc += (double)pq_s[d] * (double)kr[d];
    float sc = (float)acc;
    s_s[t] = sc;
    __syncthreads();
    int cnt = 0;
    float si = s_s[t];
    for (int j = 0; j < 256; j++) {
        float sj = s_s[j];
        cnt += (sj > si) || (sj == si && j < t);
    }
    flag[t] = (cnt < TSEL) ? 1 : 0;
    __syncthreads();
    if (cnt < TSEL) {
        int pos = 0;
        for (int j = 0; j < t; j++) pos += flag[j];
        lut[(size_t)b * TSEL + pos] = t;
    }
}

// K4: kvpart[p] += k_fm^T v (per 64-row tile); ksum += col sums.
// 2048 blocks; in-register row softmax (row-per-4-lanes); 4 partial buffers.
__global__ __launch_bounds__(256) void lin_kv(const float* __restrict__ k,
                                              const float* __restrict__ v,
                                              float* __restrict__ kvpart,
                                              float* __restrict__ ksum) {
    __shared__ float kf[64][68];
    __shared__ float vv[64][68];
    int b = blockIdx.x;            // h*128 + chunk
    int h = b >> 7, chunk = b & 127;
    int l0 = chunk * 64;
    int t = threadIdx.x;
    int row = t >> 2, d0 = (t & 3) * 16;
    const float4* ks4 = (const float4*)(k + (size_t)(l0 + row) * HD + h * 64 + d0);
    const float4* vs4 = (const float4*)(v + (size_t)(l0 + row) * HD + h * 64 + d0);
    {
        float4* vd = (float4*)&vv[row][d0];
        #pragma unroll
        for (int i = 0; i < 4; i++) vd[i] = vs4[i];
    }
    float4 X0 = ks4[0], X1 = ks4[1], X2 = ks4[2], X3 = ks4[3];
    float mx = fmaxf(fmaxf(fmaxf(X0.x, X0.y), fmaxf(X0.z, X0.w)),
                     fmaxf(fmaxf(X1.x, X1.y), fmaxf(X1.z, X1.w)));
    mx = fmaxf(mx, fmaxf(fmaxf(fmaxf(X2.x, X2.y), fmaxf(X2.z, X2.w)),
                         fmaxf(fmaxf(X3.x, X3.y), fmaxf(X3.z, X3.w))));
    mx = fmaxf(mx, __shfl_xor(mx, 1, 64));
    mx = fmaxf(mx, __shfl_xor(mx, 2, 64));
    X0.x = __expf(X0.x - mx); X0.y = __expf(X0.y - mx); X0.z = __expf(X0.z - mx); X0.w = __expf(X0.w - mx);
    X1.x = __expf(X1.x - mx); X1.y = __expf(X1.y - mx); X1.z = __expf(X1.z - mx); X1.w = __expf(X1.w - mx);
    X2.x = __expf(X2.x - mx); X2.y = __expf(X2.y - mx); X2.z = __expf(X2.z - mx); X2.w = __expf(X2.w - mx);
    X3.x = __expf(X3.x - mx); X3.y = __expf(X3.y - mx); X3.z = __expf(X3.z - mx); X3.w = __expf(X3.w - mx);
    float sm = (X0.x + X0.y + X0.z + X0.w) + (X1.x + X1.y + X1.z + X1.w)
             + (X2.x + X2.y + X2.z + X2.w) + (X3.x + X3.y + X3.z + X3.w);
    sm += __shfl_xor(sm, 1, 64);
    sm += __shfl_xor(sm, 2, 64);
    float inv = 1.f / sm;
    X0.x *= inv; X0.y *= inv; X0.z *= inv; X0.w *= inv;
    X1.x *= inv; X1.y *= inv; X1.z *= inv; X1.w *= inv;
    X2.x *= inv; X2.y *= inv; X2.z *= inv; X2.w *= inv;
    X3.x *= inv; X3.y *= inv; X3.z *= inv; X3.w *= inv;
    {
        float4* kd = (float4*)&kf[row][d0];
        kd[0] = X0; kd[1] = X1; kd[2] = X2; kd[3] = X3;
    }
    __syncthreads();
    int e_ = t & 63, dg = t >> 6;
    float acc[16];
    #pragma unroll
    for (int j = 0; j < 16; j++) acc[j] = 0.f;
    for (int l = 0; l < 64; l++) {
        float vl = vv[l][e_];
        const float4* k4 = (const float4*)&kf[l][dg * 16];
        float4 a = k4[0], b4 = k4[1], c4 = k4[2], d4 = k4[3];
        acc[0]  += a.x * vl;  acc[1]  += a.y * vl;  acc[2]  += a.z * vl;  acc[3]  += a.w * vl;
        acc[4]  += b4.x * vl; acc[5]  += b4.y * vl; acc[6]  += b4.z * vl; acc[7]  += b4.w * vl;
        acc[8]  += c4.x * vl; acc[9]  += c4.y * vl; acc[10] += c4.z * vl; acc[11] += c4.w * vl;
        acc[12] += d4.x * vl; acc[13] += d4.y * vl; acc[14] += d4.z * vl; acc[15] += d4.w * vl;
    }
    float* dst = kvpart + ((size_t)(chunk & 3) * 16 + h) * 4096;
    #pragma unroll
    for (int j = 0; j < 16; j++)
        atomicAdd(&dst[(dg * 16 + j) * 64 + e_], acc[j]);
    if (t < 64) {
        float s = 0.f;
        for (int l = 0; l < 64; l++) s += kf[l][t];
        atomicAdd(&ksum[h * 64 + t], s);
    }
}

// K5: reduce partials + KWt[h][dd][d] = sum_e kvsum[h][d][e] * W[dd][e]  (bf16, transposed)
__global__ __launch_bounds__(256) void kw_mul(const float* __restrict__ kvpart,
                                              const float* __restrict__ W,
                                              short* __restrict__ kwt) {
    __shared__ float kv[64][65];
    __shared__ float w[64][65];
    int h = blockIdx.x, t = threadIdx.x;
    for (int i = t; i < 4096; i += 256) {
        float s = 0.f;
        #pragma unroll
        for (int p = 0; p < 4; p++) s += kvpart[((size_t)p * 16 + h) * 4096 + i];
        kv[i >> 6][i & 63] = s;
        w[i >> 6][i & 63] = W[i];
    }
    __syncthreads();
    int dd = t & 63, dg = t >> 6;
    #pragma unroll
    for (int j = 0; j < 16; j++) {
        int d = dg * 16 + j;
        float a = 0.f;
        #pragma unroll 8
        for (int e = 0; e < 64; e++) a += kv[d][e] * w[dd][e];
        kwt[(size_t)h * 4096 + dd * 64 + d] = f2bf(a);
    }
}

// K6: fused block-sparse attention + linear branch. One block per (h,m), 4 waves.
// Sparse: operand-swapped MFMA (S^T/O^T), lane-resident softmax, pre-swizzled
// bf16 staging via global_load_lds, lgkm-only mid barrier.
// Linear: q_fm softmax in-reg, Ol = KWt·q_fm^T via 8 MFMAs (KWt overlaid on
// Kb[1]/Vb[1], consumed before iter-0's prefetch overwrites it).
__global__ __launch_bounds__(256) void sparse_attn_mfma(const float* __restrict__ q,
                                                        const short* __restrict__ kswz,
                                                        const short* __restrict__ vswz,
                                                        const int* __restrict__ lut,
                                                        const short* __restrict__ kwt,
                                                        const float* __restrict__ ksum,
                                                        const float* __restrict__ bproj,
                                                        float* __restrict__ out) {
    __shared__ __align__(16) short Kb[2][2048];
    __shared__ __align__(16) short Vb[2][2048];
    __shared__ __align__(16) short Pl[64][40];
    __shared__ int lut_s[TSEL];

    int b = blockIdx.x;
    int x = b & 7, jj = b >> 3;
    int h = x * 2 + (jj >> 7);       // XCD-affine: blocks on one XCD share h
    int m = jj & 127;
    int t = threadIdx.x;
    int lane = t & 63, w = t >> 6;
    int l15 = lane & 15, quad = lane >> 4;

    if (t < TSEL) lut_s[t] = lut[(size_t)(h * 128 + m) * TSEL + t];
    __syncthreads();

    // async staging: block 0 -> buf0; KWt (4096 shorts) -> Kb[1]+Vb[1]
    {
        size_t base = (size_t)(h * 256 + lut_s[0]) * 2048;
        load_lds16(kswz + base + t * 8, &Kb[0][t * 8]);
        load_lds16(vswz + base + t * 8, &Vb[0][t * 8]);
        load_lds16(kwt + (size_t)h * 4096 + t * 8, &Kb[1][t * 8]);
        load_lds16(kwt + (size_t)h * 4096 + 2048 + t * 8, &Vb[1][t * 8]);
    }

    // Q row (f32): cols {quad*8..+8} ∪ {32+quad*8..+8} of row w*16+l15
    const float* qrow = q + (size_t)(m * 64 + w * 16 + l15) * HD + h * 64;
    float4 x0 = *(const float4*)(qrow + quad * 8);
    float4 x1 = *(const float4*)(qrow + quad * 8 + 4);
    float4 x2 = *(const float4*)(qrow + 32 + quad * 8);
    float4 x3 = *(const float4*)(qrow + 32 + quad * 8 + 4);
    bf16x8 qa[2];
    qa[0] = cvt8(x0, x1);            // B-frag for QK^T (raw q, bf16)
    qa[1] = cvt8(x2, x3);

    // q_fm = softmax(q row) in f32; denom = q_fm·ksum + 1e-6
    float mx = fmaxf(fmaxf(fmaxf(x0.x, x0.y), fmaxf(x0.z, x0.w)),
                     fmaxf(fmaxf(x1.x, x1.y), fmaxf(x1.z, x1.w)));
    mx = fmaxf(mx, fmaxf(fmaxf(fmaxf(x2.x, x2.y), fmaxf(x2.z, x2.w)),
                         fmaxf(fmaxf(x3.x, x3.y), fmaxf(x3.z, x3.w))));
    mx = fmaxf(mx, __shfl_xor(mx, 16, 64));
    mx = fmaxf(mx, __shfl_xor(mx, 32, 64));
    x0.x = __expf(x0.x - mx); x0.y = __expf(x0.y - mx); x0.z = __expf(x0.z - mx); x0.w = __expf(x0.w - mx);
    x1.x = __expf(x1.x - mx); x1.y = __expf(x1.y - mx); x1.z = __expf(x1.z - mx); x1.w = __expf(x1.w - mx);
    x2.x = __expf(x2.x - mx); x2.y = __expf(x2.y - mx); x2.z = __expf(x2.z - mx); x2.w = __expf(x2.w - mx);
    x3.x = __expf(x3.x - mx); x3.y = __expf(x3.y - mx); x3.z = __expf(x3.z - mx); x3.w = __expf(x3.w - mx);
    float sm = (x0.x + x0.y + x0.z + x0.w) + (x1.x + x1.y + x1.z + x1.w)
             + (x2.x + x2.y + x2.z + x2.w) + (x3.x + x3.y + x3.z + x3.w);
    sm += __shfl_xor(sm, 16, 64);
    sm += __shfl_xor(sm, 32, 64);
    float qsc = 1.f / sm;
    float4 ka0 = *(const float4*)(ksum + h * 64 + quad * 8);
    float4 ka1 = *(const float4*)(ksum + h * 64 + quad * 8 + 4);
    float4 ka2 = *(const float4*)(ksum + h * 64 + 32 + quad * 8);
    float4 ka3 = *(const float4*)(ksum + h * 64 + 32 + quad * 8 + 4);
    float dq = x0.x * ka0.x + x0.y * ka0.y + x0.z * ka0.z + x0.w * ka0.w
             + x1.x * ka1.x + x1.y * ka1.y + x1.z * ka1.z + x1.w * ka1.w
             + x2.x * ka2.x + x2.y * ka2.y + x2.z * ka2.z + x2.w * ka2.w
             + x3.x * ka3.x + x3.y * ka3.y + x3.z * ka3.z + x3.w * ka3.w;
    dq += __shfl_xor(dq, 16, 64);
    dq += __shfl_xor(dq, 32, 64);
    float invd = 1.f / (dq * qsc + 1e-6f);
    x0.x *= qsc; x0.y *= qsc; x0.z *= qsc; x0.w *= qsc;
    x1.x *= qsc; x1.y *= qsc; x1.z *= qsc; x1.w *= qsc;
    x2.x *= qsc; x2.y *= qsc; x2.z *= qsc; x2.w *= qsc;
    x3.x *= qsc; x3.y *= qsc; x3.z *= qsc; x3.w *= qsc;
    bf16x8 qf[2];
    qf[0] = cvt8(x0, x1);            // B-frag of q_fm^T
    qf[1] = cvt8(x2, x3);

    __syncthreads();                 // drains vmcnt: buf0 + KWt visible

    // Ol^T[dd][row] = KWt · q_fm^T  (C layout identical to sparse O)
    // KWt linear in LDS: Kb[1] holds dd 0..31, Vb[1] holds dd 32..63.
    f32x4 Ol[4];
    #pragma unroll
    for (int dt = 0; dt < 4; dt++) Ol[dt] = (f32x4){0.f, 0.f, 0.f, 0.f};
    #pragma unroll
    for (int dt = 0; dt < 4; dt++) {
        #pragma unroll
        for (int kc = 0; kc < 2; kc++) {
            int flat = (dt * 16 + l15) * 64 + kc * 32 + quad * 8;
            bf16x8 a = (dt < 2) ? *(const bf16x8*)&Kb[1][flat]
                                : *(const bf16x8*)&Vb[1][flat - 2048];
            Ol[dt] = __builtin_amdgcn_mfma_f32_16x16x32_bf16(a, qf[kc], Ol[dt], 0, 0, 0);
        }
    }

    f32x4 O[4];
    #pragma unroll
    for (int dt = 0; dt < 4; dt++) O[dt] = (f32x4){0.f, 0.f, 0.f, 0.f};
    float l_i = 0.f;
    const f32x4 z = (f32x4){0.f, 0.f, 0.f, 0.f};

    for (int ti = 0; ti < TSEL; ti++) {
        __syncthreads();              // B1: staging for ti complete; KWt reads done (ti=0)
        int buf = ti & 1;
        if (ti + 1 < TSEL) {          // prefetch ti+1 (in flight across B2)
            size_t base = (size_t)(h * 256 + lut_s[ti + 1]) * 2048;
            load_lds16(kswz + base + t * 8, &Kb[buf ^ 1][t * 8]);
            load_lds16(vswz + base + t * 8, &Vb[buf ^ 1][t * 8]);
        }
        // S^T = K · Q^T
        int r0 = l15, r1 = 16 + l15;
        bf16x8 a00 = *(const bf16x8*)&Kb[buf][(r0 * 8 + (quad ^ (r0 & 7))) * 8];
        bf16x8 a01 = *(const bf16x8*)&Kb[buf][(r0 * 8 + ((4 + quad) ^ (r0 & 7))) * 8];
        bf16x8 a10 = *(const bf16x8*)&Kb[buf][(r1 * 8 + (quad ^ (r1 & 7))) * 8];
        bf16x8 a11 = *(const bf16x8*)&Kb[buf][(r1 * 8 + ((4 + quad) ^ (r1 & 7))) * 8];
        f32x4 s0 = __builtin_amdgcn_mfma_f32_16x16x32_bf16(a00, qa[0], z, 0, 0, 0);
        s0 = __builtin_amdgcn_mfma_f32_16x16x32_bf16(a01, qa[1], s0, 0, 0, 0);
        f32x4 s1 = __builtin_amdgcn_mfma_f32_16x16x32_bf16(a10, qa[0], z, 0, 0, 0);
        s1 = __builtin_amdgcn_mfma_f32_16x16x32_bf16(a11, qa[1], s1, 0, 0, 0);

        // p = exp(s*scale), fixed max (|s*scale| small)
        float p0[4], p1[4];
        float lsum = 0.f;
        #pragma unroll
        for (int r = 0; r < 4; r++) {
            p0[r] = __expf(s0[r] * 0.125f);
            p1[r] = __expf(s1[r] * 0.125f);
            lsum += p0[r] + p1[r];
        }
        lsum += __shfl_xor(lsum, 16, 64);
        lsum += __shfl_xor(lsum, 32, 64);
        l_i += lsum;

        #pragma unroll
        for (int r = 0; r < 4; r++) {
            Pl[w * 16 + l15][quad * 4 + r] = f2bf(p0[r]);
            Pl[w * 16 + l15][16 + quad * 4 + r] = f2bf(p1[r]);
        }

        // B2: LDS-only barrier — async prefetch stays in flight
        asm volatile("s_waitcnt lgkmcnt(0)\n\ts_barrier" ::: "memory");

        // O^T += V^T · P^T
        bf16x8 pb = *(const bf16x8*)&Pl[w * 16 + l15][quad * 8];
        #pragma unroll
        for (int dt = 0; dt < 4; dt++) {
            int d = dt * 16 + l15;
            bf16x8 va = *(const bf16x8*)&Vb[buf][(d * 4 + (quad ^ ((d >> 1) & 3))) * 8];
            O[dt] = __builtin_amdgcn_mfma_f32_16x16x32_bf16(va, pb, O[dt], 0, 0, 0);
        }
    }

    float inv = 1.f / l_i;
    float* dst = out + (size_t)(m * 64 + w * 16 + l15) * HD + h * 64;
    #pragma unroll
    for (int dt = 0; dt < 4; dt++) {
        float4 bv = *(const float4*)(bproj + dt * 16 + quad * 4);
        float4 o;
        o.x = O[dt][0] * inv + Ol[dt][0] * invd + bv.x;
        o.y = O[dt][1] * inv + Ol[dt][1] * invd + bv.y;
        o.z = O[dt][2] * inv + Ol[dt][2] * invd + bv.z;
        o.w = O[dt][3] * inv + Ol[dt][3] * invd + bv.w;
        *(float4*)(dst + dt * 16 + quad * 4) = o;
    }
}

extern "C" void kernel_launch(void* const* d_in, const int* in_sizes, int n_in,
                              void* d_out, int out_size, void* d_ws, size_t ws_size,
                              hipStream_t stream) {
    const float* q  = (const float*)d_in[0];
    const float* k  = (const float*)d_in[1];
    const float* v  = (const float*)d_in[2];
    const float* W  = (const float*)d_in[3];
    const float* bp = (const float*)d_in[4];
    float* out = (float*)d_out;
    float* ws = (float*)d_ws;

    float* kvpart = ws + OFF_KVPART;
    float* ksum   = ws + OFF_KSUM;
    float* pk     = ws + OFF_PK;
    short* kwt    = (short*)(ws + OFF_KWT);
    short* kswz   = (short*)(ws + OFF_KSWZ);
    short* vswz   = kswz + (size_t)16 * 256 * 2048;
    float* pq     = ws + OFF_PQ;      // overlays kvpart (safe: written post-kw_mul)
    int*   lut    = (int*)(ws + OFF_LUT);

    hipMemsetAsync(ws, 0, OFF_ZEND * sizeof(float), stream);
    prep_kv<<<4096, 256, 0, stream>>>(k, v, kswz, vswz, pk);
    lin_kv<<<2048, 256, 0, stream>>>(k, v, kvpart, ksum);
    kw_mul<<<16, 256, 0, stream>>>(kvpart, W, kwt);
    pool_q<<<2048, 64, 0, stream>>>(q, pq);
    score_topk<<<2048, 256, 0, stream>>>(pq, pk, lut);
    sparse_attn_mfma<<<2048, 256, 0, stream>>>(q, kswz, vswz, lut, kwt, ksum, bp, out);
}